// Round 9
// baseline (460.421 us; speedup 1.0000x reference)
//
#include <hip/hip_runtime.h>
#include <stdint.h>
#include <math.h>

#define NN 128
#define EE 256
#define HH 256

#define OFF_LOGP 0
#define OFF_IDX  32768
#define OFF_INIT 65536
#define OFF_LAST 66048
#define OFF_RS   66560

// fallback path key stride
#define KST  260
#define KST4 65

__device__ __forceinline__ uint32_t rotl32_(uint32_t x, int d){ return (x<<d)|(x>>(32-d)); }

// Threefry-2x32, 20 rounds, JAX key schedule (bit-identical to rounds 1-7)
__device__ __forceinline__ void tf2x32(uint32_t k0, uint32_t k1, uint32_t x0, uint32_t x1,
                                       uint32_t& o0, uint32_t& o1){
  uint32_t k2 = k0 ^ k1 ^ 0x1BD11BDAu;
  x0 += k0; x1 += k1;
#define TF_RND(r) { x0 += x1; x1 = rotl32_(x1,(r)); x1 ^= x0; }
  TF_RND(13) TF_RND(15) TF_RND(26) TF_RND(6)
  x0 += k1; x1 += k2 + 1u;
  TF_RND(17) TF_RND(29) TF_RND(16) TF_RND(24)
  x0 += k2; x1 += k0 + 2u;
  TF_RND(13) TF_RND(15) TF_RND(26) TF_RND(6)
  x0 += k0; x1 += k1 + 3u;
  TF_RND(17) TF_RND(29) TF_RND(16) TF_RND(24)
  x0 += k1; x1 += k2 + 4u;
  TF_RND(13) TF_RND(15) TF_RND(26) TF_RND(6)
  x0 += k2; x1 += k0 + 5u;
#undef TF_RND
  o0 = x0; o1 = x1;
}

// Refined fast tanh (rounds 4-7, passed): ~0.5 ulp division
__device__ __forceinline__ float fast_tanhf(float x){
  float ax = __builtin_fabsf(x);
  float E = __builtin_amdgcn_exp2f(ax * -2.885390081777927f);
  float num = 1.0f - E;
  float den = 1.0f + E;
  float inv = __builtin_amdgcn_rcpf(den);
  inv = fmaf(fmaf(-den, inv, 1.0f), inv, inv);
  float r = num * inv;
  r = fmaf(fmaf(-den, r, num), inv, r);
  return __builtin_copysignf(r, x);
}

// k_tab inner tanh on PRE-SCALED input xs = x * 2*log2(e) (round-7, passed)
__device__ __forceinline__ float tanh_pre(float xs){
  float E = __builtin_amdgcn_exp2f(xs);
  return fmaf(-2.0f, __builtin_amdgcn_rcpf(1.0f + E), 1.0f);
}

// jax.random.gumbel element — bit-identical to rounds 1-7
__device__ __forceinline__ float jax_gumbel(uint32_t k0, uint32_t k1, uint32_t t){
  uint32_t o0, o1, bits;
  tf2x32(k0, k1, 0u, t, o0, o1);
  bits = o0 ^ o1;
  float u = __uint_as_float((bits >> 9) | 0x3f800000u) - 1.0f;
  const float kTiny = 1.17549435e-38f;
  u = fmaxf(kTiny, u + kTiny);
  return -logf(-logf(u));
}

// Wave-wide argmax(+sum) reduce (bit-identical to rounds 5-7)
#define CMB_DPP(CTRL) { \
  float ny_ = __int_as_float(__builtin_amdgcn_mov_dpp(__float_as_int(y), (CTRL), 0xf, 0xf, false)); \
  int   nj_ = __builtin_amdgcn_mov_dpp(pj, (CTRL), 0xf, 0xf, false); \
  float ne_ = __int_as_float(__builtin_amdgcn_mov_dpp(__float_as_int(es), (CTRL), 0xf, 0xf, false)); \
  es += ne_; \
  if (ny_ > y || (ny_ == y && nj_ < pj)){ y = ny_; pj = nj_; } }
#define CMB_SWZ16() { \
  float ny_ = __int_as_float(__builtin_amdgcn_ds_swizzle(__float_as_int(y), 0x401F)); \
  int   nj_ = __builtin_amdgcn_ds_swizzle(pj, 0x401F); \
  float ne_ = __int_as_float(__builtin_amdgcn_ds_swizzle(__float_as_int(es), 0x401F)); \
  es += ne_; \
  if (ny_ > y || (ny_ == y && nj_ < pj)){ y = ny_; pj = nj_; } }
#define CMB_SHF32() { \
  float ny_ = __shfl_xor(y, 32); \
  int   nj_ = __shfl_xor(pj, 32); \
  float ne_ = __shfl_xor(es, 32); \
  es += ne_; \
  if (ny_ > y || (ny_ == y && nj_ < pj)){ y = ny_; pj = nj_; } }

// ============ K1: fused precompute + optional gumbel table ============
// blocks: 0 = tmp1+c0 | 1..512 = T1 | 513..768 = base | 769..1024 = gumbel (if g_tab)
__global__ __launch_bounds__(256) void k_pre(
    const float* __restrict__ liw, const float* __restrict__ Wr,
    const float* __restrict__ Wq, const float* __restrict__ lcv,
    const float* __restrict__ Whbar, const float* __restrict__ bhbar,
    const float* __restrict__ brest, const float* __restrict__ bq,
    float* __restrict__ c0, float* __restrict__ T1, float* __restrict__ base,
    float* __restrict__ g_tab)
{
  __shared__ float sbuf[512];
  __shared__ uint32_t gk0[NN], gk1[NN];
  const int bid = blockIdx.x;
  const int t = threadIdx.x;
  if (bid == 0){
    float acc = 0.f;
    for (int k = 0; k < 2*EE; ++k) acc = fmaf(liw[k], Wr[(size_t)k*EE + t], acc);
    sbuf[t] = acc;
    __syncthreads();
    float c = 0.f;
    for (int e = 0; e < EE; ++e) c = fmaf(sbuf[e], Wq[(size_t)e*HH + t], c);
    c0[t] = c;
  } else if (bid <= 512){
    const int r = bid - 1;
    float acc = 0.f;
    for (int e = 0; e < EE; ++e) acc = fmaf(Wr[(size_t)r*EE + e], Wq[(size_t)e*HH + t], acc);
    T1[(size_t)r*HH + t] = acc;
  } else if (bid <= 768){
    const int b = bid - 513;
    float* sm  = sbuf;
    float* hb2 = sbuf + 256;
    float acc = 0.f;
    const float* p = lcv + (size_t)b*NN*EE + t;
    for (int n = 0; n < NN; ++n) acc += p[(size_t)n*EE];
    sm[t] = acc * 0.0078125f;
    __syncthreads();
    float a2 = 0.f;
    for (int e = 0; e < EE; ++e) a2 = fmaf(sm[e], Whbar[(size_t)e*EE + t], a2);
    hb2[t] = (a2 + bhbar[t]) + brest[t];
    __syncthreads();
    float a3 = 0.f;
    for (int e = 0; e < EE; ++e) a3 = fmaf(hb2[e], Wq[(size_t)e*HH + t], a3);
    base[(size_t)b*HH + t] = a3 + bq[t];
  } else {
    // gumbel table for batch b2 (bit-identical values to k_seq's internal gen)
    const int b2 = bid - 769;
    if (t < NN){
      uint32_t o0, o1; tf2x32(0u, 42u, 0u, (uint32_t)t, o0, o1);
      gk0[t] = o0; gk1[t] = o1;
    }
    __syncthreads();
    for (int k = 0; k < 64; ++k){
      const int p = t + 256*k;
      const int i = p >> 7, j = p & 127;
      g_tab[(size_t)b2*16384 + p] = jax_gumbel(gk0[i], gk1[i], (uint32_t)(b2*NN + j));
    }
  }
}

// ============ K2: keys/P2 GEMM + fused l0 row + fused idx0 + qb ============
__global__ __launch_bounds__(1024) void k_keysP2(
    const float* __restrict__ lcv, const float* __restrict__ Wk,
    const float* __restrict__ T1, const float* __restrict__ bk,
    const float* __restrict__ base, const float* __restrict__ c0,
    const float* __restrict__ vvec, const int* __restrict__ mask_in,
    const int* __restrict__ id_in,
    float* __restrict__ keysg, float* __restrict__ P2g, float* __restrict__ ltab,
    float* __restrict__ qbg)
{
  const int b = blockIdx.x, tid = threadIdx.x, wid = tid >> 6, lane = tid & 63;
  __shared__ __align__(16) float sbuf[20992];   // sA[128][36] + sW[32][256] + sT[32][256]
  __shared__ __align__(16) float q0s[EE];
  __shared__ __align__(16) float vs[EE];
  __shared__ float l0s[NN];
  __shared__ int idx_sh;
  float* sA = sbuf;
  float* sW = sbuf + 4608;
  float* sT = sbuf + 12800;
  if (tid < 64){
    float4 bs = ((const float4*)(base + (size_t)b*HH))[tid];
    const float4 cc = ((const float4*)c0)[tid];
    bs.x += cc.x; bs.y += cc.y; bs.z += cc.z; bs.w += cc.w;
    ((float4*)q0s)[tid] = bs;
    ((float4*)vs)[tid]  = ((const float4*)vvec)[tid];
  }
  float4 kacc[8], p2acc[8];
  #pragma unroll
  for (int r = 0; r < 8; ++r){
    kacc[r]  = make_float4(0.f,0.f,0.f,0.f);
    p2acc[r] = make_float4(0.f,0.f,0.f,0.f);
  }
  for (int ch = 0; ch < 8; ++ch){
    const int e0 = ch << 5;
    __syncthreads();
    {
      const int r = tid >> 3, c = tid & 7;
      const float4 t = ((const float4*)(lcv + ((size_t)b*NN + r)*EE + e0))[c];
      ((float4*)sA)[r*9 + c] = t;
    }
    #pragma unroll
    for (int s = 0; s < 2; ++s){
      const int idx4 = s*1024 + tid;
      const int e = idx4 >> 6, c = idx4 & 63;
      ((float4*)sW)[idx4] = ((const float4*)(Wk + (size_t)(e0+e)*HH))[c];
      ((float4*)sT)[idx4] = ((const float4*)(T1 + (size_t)(EE+e0+e)*HH))[c];
    }
    __syncthreads();
    const float* aRow = sA + (wid << 3)*36;
    for (int e = 0; e < 32; ++e){
      const float4 wv = ((const float4*)sW)[(e<<6) + lane];
      const float4 tv = ((const float4*)sT)[(e<<6) + lane];
      #pragma unroll
      for (int r = 0; r < 8; ++r){
        const float av = aRow[r*36 + e];
        kacc[r].x = fmaf(av, wv.x, kacc[r].x);
        kacc[r].y = fmaf(av, wv.y, kacc[r].y);
        kacc[r].z = fmaf(av, wv.z, kacc[r].z);
        kacc[r].w = fmaf(av, wv.w, kacc[r].w);
        p2acc[r].x = fmaf(av, tv.x, p2acc[r].x);
        p2acc[r].y = fmaf(av, tv.y, p2acc[r].y);
        p2acc[r].z = fmaf(av, tv.z, p2acc[r].z);
        p2acc[r].w = fmaf(av, tv.w, p2acc[r].w);
      }
    }
  }
  const float4 bkv = ((const float4*)bk)[lane];
  const float4 qv0 = ((const float4*)q0s)[lane];
  const float4 vv0 = ((const float4*)vs)[lane];
  #pragma unroll
  for (int r = 0; r < 8; ++r){
    const int j = (wid << 3) + r;
    float4 kv = kacc[r];
    kv.x += bkv.x; kv.y += bkv.y; kv.z += bkv.z; kv.w += bkv.w;
    ((float4*)(keysg + ((size_t)b*NN + j)*EE))[lane] = kv;
    ((float4*)(P2g   + ((size_t)b*NN + j)*EE))[lane] = p2acc[r];
    float p = 0.f;
    p = fmaf(fast_tanhf(kv.x + qv0.x), vv0.x, p);
    p = fmaf(fast_tanhf(kv.y + qv0.y), vv0.y, p);
    p = fmaf(fast_tanhf(kv.z + qv0.z), vv0.z, p);
    p = fmaf(fast_tanhf(kv.w + qv0.w), vv0.w, p);
    #pragma unroll
    for (int off = 1; off < 64; off <<= 1) p += __shfl_xor(p, off);
    if (lane == 0){
      const float lv = 10.0f * fast_tanhf(p);
      ltab[((size_t)b*129 + 128)*NN + j] = lv;
      l0s[j] = lv;
    }
  }
  __syncthreads();
  // fused idx0 (identical algorithm/values to round-6/7 k_idx0qb)
  if (tid < 64){
    const float NEG_INF = -__builtin_huge_valf();
    float l0 = l0s[lane];
    float l1 = l0s[64 + lane];
    if (mask_in[(size_t)b*NN + lane])      l0 = NEG_INF;
    if (mask_in[(size_t)b*NN + 64 + lane]) l1 = NEG_INF;
    uint32_t k0, k1; tf2x32(0u, 42u, 0u, 0u, k0, k1);
    const float g0 = jax_gumbel(k0, k1, (uint32_t)(b*NN + lane));
    const float g1 = jax_gumbel(k0, k1, (uint32_t)(b*NN + 64 + lane));
    float y = l0 + g0; int pj = lane;
    { float yb = l1 + g1; if (yb > y){ y = yb; pj = 64 + lane; } }
    float es = 0.f;   // unused
    CMB_DPP(0xB1); CMB_DPP(0x4E); CMB_DPP(0x124); CMB_DPP(0x128);
    CMB_SWZ16(); CMB_SHF32();
    int bi = pj;
    if (id_in[0] == 0) bi = 0;
    if (lane == 0) idx_sh = bi;
  }
  __syncthreads();
  // fused qb GEMV (identical sequential e-order)
  if (tid < HH){
    const float* arow = lcv + ((size_t)b*NN + idx_sh)*EE;
    float acc = 0.f;
    #pragma unroll 4
    for (int e = 0; e < EE; ++e) acc = fmaf(arow[e], T1[(size_t)e*HH + tid], acc);
    qbg[(size_t)b*HH + tid] = base[(size_t)b*HH + tid] + acc;
  }
}

// ============ K3: the big table — 3 blocks/CU, 16-idx chunks ============
// l_tab[b][idx][j] = 10*tanh(sum_h tanh_pre(ckeys[j,h] + cQ2[idx,h]) * v[h])
// Per-element op sequence and hc 0..63 accumulation order IDENTICAL to round 7.
// FIX vs round 8: read swizzle masked to 3 bits to match write swizzle
// ((row>>1)&7) — round 8 used jp>>1 unmasked (wrong for rows 16..31).
__global__ __launch_bounds__(256) void k_tab(
    const float* __restrict__ keysg, const float* __restrict__ P2g,
    const float* __restrict__ qb, const float* __restrict__ vvec,
    float* __restrict__ l_tab)
{
  const int b  = blockIdx.x >> 2;
  const int jt = blockIdx.x & 3;
  const int t = threadIdx.x;
  const float CSC = 2.885390081777927f;            // 2*log2(e)
  __shared__ __align__(16) float skeys[32*65*4];   // 33280 B, *CSC, swz (row>>1)&7
  __shared__ __align__(16) float sQ2[16*65*4];     // 16640 B, (P2+qb)*CSC
  __shared__ __align__(16) float sv[EE];
  __shared__ __align__(16) float sqbc[EE];         // qb*CSC
  // total LDS 51968 B -> 3 blocks/CU (12 waves)

  #pragma unroll
  for (int k = 0; k < 8; ++k){
    const int idx4 = t + 256*k;                // 0..2047
    const int row = idx4 >> 6, hc = idx4 & 63;
    float4 kv = ((const float4*)(keysg + ((size_t)b*NN + jt*32 + row)*EE))[hc];
    kv.x *= CSC; kv.y *= CSC; kv.z *= CSC; kv.w *= CSC;
    ((float4*)skeys)[row*65 + (hc ^ ((row >> 1) & 7))] = kv;
  }
  if (t < 64){
    ((float4*)sv)[t]  = ((const float4*)vvec)[t];
    float4 qv = ((const float4*)(qb + (size_t)b*HH))[t];
    qv.x *= CSC; qv.y *= CSC; qv.z *= CSC; qv.w *= CSC;
    ((float4*)sqbc)[t] = qv;
  }
  const int iq = t >> 4;         // idx slot within 16-chunk
  const int jq = (t >> 1) & 7;   // j-quad
  const int s  = t & 1;          // pair-half
  const int jp = jq*4 + s*2;     // 2 owned j rows: jp, jp+1
  const int swz = (jp >> 1) & 7; // matches write swizzle for rows jp, jp+1 (jp even)

  // prefetch P2 chunk for ib=0
  float4 pr[4];
  #pragma unroll
  for (int k = 0; k < 4; ++k){
    const int idx4 = t + 256*k;
    const int row = idx4 >> 6, hc = idx4 & 63;
    pr[k] = ((const float4*)(P2g + ((size_t)b*NN + row)*EE))[hc];
  }

  for (int ib = 0; ib < 8; ++ib){
    __syncthreads();
    #pragma unroll
    for (int k = 0; k < 4; ++k){
      const int idx4 = t + 256*k;
      const int row = idx4 >> 6, hc = idx4 & 63;
      const float4 qv = ((const float4*)sqbc)[hc];
      float4 pv;
      pv.x = fmaf(pr[k].x, CSC, qv.x);
      pv.y = fmaf(pr[k].y, CSC, qv.y);
      pv.z = fmaf(pr[k].z, CSC, qv.z);
      pv.w = fmaf(pr[k].w, CSC, qv.w);
      ((float4*)sQ2)[row*65 + hc] = pv;
    }
    if (ib + 1 < 8){
      #pragma unroll
      for (int k = 0; k < 4; ++k){
        const int idx4 = t + 256*k;
        const int row = idx4 >> 6, hc = idx4 & 63;
        pr[k] = ((const float4*)(P2g + ((size_t)b*NN + (ib+1)*16 + row)*EE))[hc];
      }
    }
    __syncthreads();
    float a0 = 0.f, a1 = 0.f;
    const float4* krow0 = (const float4*)skeys + (size_t)jp*65;
    const float4* krow1 = (const float4*)skeys + (size_t)(jp + 1)*65;
    const float4* qrow  = (const float4*)sQ2   + (size_t)iq*65;
    #pragma unroll 16
    for (int hc = 0; hc < 64; ++hc){
      const float4 qv = qrow[hc];
      const float4 vv = ((const float4*)sv)[hc];
      const int hx = hc ^ swz;
      const float4 k0 = krow0[hx];
      const float4 k1 = krow1[hx];
      a0 = fmaf(tanh_pre(k0.x + qv.x), vv.x, a0);
      a0 = fmaf(tanh_pre(k0.y + qv.y), vv.y, a0);
      a0 = fmaf(tanh_pre(k0.z + qv.z), vv.z, a0);
      a0 = fmaf(tanh_pre(k0.w + qv.w), vv.w, a0);
      a1 = fmaf(tanh_pre(k1.x + qv.x), vv.x, a1);
      a1 = fmaf(tanh_pre(k1.y + qv.y), vv.y, a1);
      a1 = fmaf(tanh_pre(k1.z + qv.z), vv.z, a1);
      a1 = fmaf(tanh_pre(k1.w + qv.w), vv.w, a1);
    }
    const int idx = ib*16 + iq;
    float* dst = l_tab + ((size_t)b*129 + idx)*NN + jt*32 + jp;
    dst[0] = 10.0f * fast_tanhf(a0);
    dst[1] = 10.0f * fast_tanhf(a1);
  }
}

// ============ K4: sequential sampler (g_tab-aware) ============
__global__ __launch_bounds__(256) void k_seq(
    const float* __restrict__ l_tab, const float* __restrict__ onode,
    const int* __restrict__ mask_in, const int* __restrict__ id_in,
    const float* __restrict__ g_tab, float* __restrict__ out)
{
  const int b = blockIdx.x;
  const int tid = threadIdx.x;
  const int wid = tid >> 6;
  const int lane = tid & 63;
  __shared__ float l_s[129*NN];      // 66048 B
  __shared__ float g_a[NN*NN];       // 65536 B
  __shared__ float2 on_s[NN];
  __shared__ int   mask_s[NN];
  __shared__ uint32_t sk0[NN], sk1[NN];

  #pragma unroll
  for (int k = 0; k < 17; ++k){
    const int i4 = tid + 256*k;
    if (i4 < (129*NN)/4)
      ((float4*)l_s)[i4] = ((const float4*)(l_tab + (size_t)b*129*NN))[i4];
  }
  if (tid < NN){
    mask_s[tid] = mask_in[(size_t)b*NN + tid];
    on_s[tid] = ((const float2*)onode)[b*NN + tid];
    if (!g_tab){
      uint32_t o0, o1; tf2x32(0u, 42u, 0u, (uint32_t)tid, o0, o1);
      sk0[tid] = o0; sk1[tid] = o1;
    }
  }
  if (g_tab){
    #pragma unroll
    for (int k = 0; k < 16; ++k)
      ((float4*)g_a)[tid + 256*k] = ((const float4*)(g_tab + (size_t)b*16384))[tid + 256*k];
    __syncthreads();
  } else {
    __syncthreads();
    for (int k = 0; k < 64; ++k){
      const int p = tid + 256*k;
      const int i = p >> 7, j = p & 127;
      g_a[p] = jax_gumbel(sk0[i], sk1[i], (uint32_t)(b*NN + j));
    }
    __syncthreads();
  }
  if (wid != 0) return;

  const int id0 = id_in[0];
  const float NEG_INF = -__builtin_huge_valf();
  if (lane == 0){
    out[OFF_INIT + 2*b]     = on_s[0].x;
    out[OFF_INIT + 2*b + 1] = on_s[0].y;
  }
  int prev = 128, cur = 0;
  for (int i = 0; i < NN; ++i){
    float l0 = l_s[prev*NN + lane];
    float l1 = l_s[prev*NN + 64 + lane];
    if (mask_s[lane])      l0 = NEG_INF;
    if (mask_s[64 + lane]) l1 = NEG_INF;
    float y = l0 + g_a[i*NN + lane]; int pj = lane;
    { float yb = l1 + g_a[i*NN + 64 + lane];
      if (yb > y){ y = yb; pj = 64 + lane; } }
    float es = __expf(l0) + __expf(l1);
    CMB_DPP(0xB1); CMB_DPP(0x4E); CMB_DPP(0x124); CMB_DPP(0x128);
    CMB_SWZ16(); CMB_SHF32();
    int bi = pj;
    if (i == 0 && id0 == 0) bi = 0;
    const float lsel = __shfl((bi & 64) ? l1 : l0, bi & 63);
    const float logp = lsel - __logf(es);
    if (lane == 0){
      out[OFF_LOGP + b*NN + i] = logp;
      out[OFF_IDX  + b*NN + i] = (float)bi;
      const float2 pc = on_s[cur];
      const float2 pn = on_s[bi];
      const float dx = pn.x - pc.x, dy = pn.y - pc.y;
      out[OFF_RS + b*NN + i] = sqrtf(dx*dx + dy*dy);
      if (i == NN-1){ out[OFF_LAST + 2*b] = pn.x; out[OFF_LAST + 2*b + 1] = pn.y; }
      mask_s[bi] = 1;
      cur = bi;
    }
    prev = bi;
  }
}

// ================= FALLBACK path kernels (round-4, known-pass) =================
__global__ void k_tmp1(const float* __restrict__ liw, const float* __restrict__ Wr,
                       float* __restrict__ tmp1){
  int e = threadIdx.x;
  float acc = 0.f;
  for (int k = 0; k < 2*EE; ++k) acc = fmaf(liw[k], Wr[(size_t)k*EE + e], acc);
  tmp1[e] = acc;
}

__global__ void k_T1(const float* __restrict__ Wr, const float* __restrict__ Wq,
                     float* __restrict__ T1){
  int r = blockIdx.x, h = threadIdx.x;
  float acc = 0.f;
  for (int e = 0; e < EE; ++e) acc = fmaf(Wr[(size_t)r*EE + e], Wq[(size_t)e*HH + h], acc);
  T1[(size_t)r*HH + h] = acc;
}

__global__ void k_base(const float* __restrict__ lcv, const float* __restrict__ Whbar,
                       const float* __restrict__ bhbar, const float* __restrict__ brest,
                       const float* __restrict__ Wq, const float* __restrict__ bq,
                       float* __restrict__ base){
  __shared__ float sm[EE];
  __shared__ float hb2[EE];
  int b = blockIdx.x, t = threadIdx.x;
  float acc = 0.f;
  const float* p = lcv + (size_t)b*NN*EE + t;
  for (int n = 0; n < NN; ++n) acc += p[(size_t)n*EE];
  sm[t] = acc * 0.0078125f;
  __syncthreads();
  float a2 = 0.f;
  for (int e = 0; e < EE; ++e) a2 = fmaf(sm[e], Whbar[(size_t)e*EE + t], a2);
  hb2[t] = (a2 + bhbar[t]) + brest[t];
  __syncthreads();
  float a3 = 0.f;
  for (int e = 0; e < EE; ++e) a3 = fmaf(hb2[e], Wq[(size_t)e*HH + t], a3);
  base[(size_t)b*HH + t] = a3 + bq[t];
}

__global__ __launch_bounds__(1024, 4) void dec_main(
    const float* __restrict__ lcv, const float* __restrict__ onode,
    const int* __restrict__ mask_in, const int* __restrict__ id_in,
    const float* __restrict__ Wk, const float* __restrict__ bk,
    const float* __restrict__ vvec, const float* __restrict__ T1,
    const float* __restrict__ base, const float* __restrict__ tmp1,
    const float* __restrict__ Wq, float* __restrict__ out)
{
  const int b = blockIdx.x;
  const int tid = threadIdx.x;
  const int wid = tid >> 6;
  const int lane = tid & 63;

  __shared__ __align__(16) float keys_lds[NN*KST];
  __shared__ __align__(16) float q_s[272];
  __shared__ __align__(16) float base_s[HH];
  __shared__ __align__(16) float p1row[HH];
  __shared__ __align__(16) float2 on_s[NN];
  __shared__ float u_s[NN];
  __shared__ float g2_s[2][NN];
  __shared__ int act_s[NN];
  __shared__ int pos_s[NN];
  __shared__ int mask_s[NN];
  __shared__ uint32_t sk0[NN], sk1[NN];
  __shared__ int idx_sh, L_sh;

  const float NEG_INF = -__builtin_huge_valf();
  const int id0 = id_in[0];

  float4 kacc[8], p2acc[8];
  #pragma unroll
  for (int r = 0; r < 8; ++r){
    kacc[r]  = make_float4(0.f,0.f,0.f,0.f);
    p2acc[r] = make_float4(0.f,0.f,0.f,0.f);
  }
  {
    float* sA = keys_lds;
    float* sW = keys_lds + 4608;
    float* sT = keys_lds + 12800;
    for (int ch = 0; ch < 8; ++ch){
      const int e0 = ch << 5;
      __syncthreads();
      {
        const int r = tid >> 3, c = tid & 7;
        const float4 t = ((const float4*)(lcv + ((size_t)b*NN + r)*EE + e0))[c];
        ((float4*)sA)[r*9 + c] = t;
      }
      #pragma unroll
      for (int s = 0; s < 2; ++s){
        const int idx4 = s*1024 + tid;
        const int e = idx4 >> 6, c = idx4 & 63;
        ((float4*)sW)[idx4] = ((const float4*)(Wk + (size_t)(e0+e)*HH))[c];
        ((float4*)sT)[idx4] = ((const float4*)(T1 + (size_t)(EE+e0+e)*HH))[c];
      }
      __syncthreads();
      const float* aRow = sA + (wid << 3)*36;
      for (int e = 0; e < 32; ++e){
        const float4 wv = ((const float4*)sW)[(e<<6) + lane];
        const float4 tv = ((const float4*)sT)[(e<<6) + lane];
        #pragma unroll
        for (int r = 0; r < 8; ++r){
          const float av = aRow[r*36 + e];
          kacc[r].x = fmaf(av, wv.x, kacc[r].x);
          kacc[r].y = fmaf(av, wv.y, kacc[r].y);
          kacc[r].z = fmaf(av, wv.z, kacc[r].z);
          kacc[r].w = fmaf(av, wv.w, kacc[r].w);
          p2acc[r].x = fmaf(av, tv.x, p2acc[r].x);
          p2acc[r].y = fmaf(av, tv.y, p2acc[r].y);
          p2acc[r].z = fmaf(av, tv.z, p2acc[r].z);
          p2acc[r].w = fmaf(av, tv.w, p2acc[r].w);
        }
      }
    }
  }
  __syncthreads();
  {
    const float4 bkv = ((const float4*)bk)[lane];
    const int sphys = ((lane >> 4) << 4) | ((lane & 15) ^ (lane >> 4));
    #pragma unroll
    for (int r = 0; r < 8; ++r){
      const int j = (wid << 3) + r;
      float4 kv = kacc[r];
      kv.x += bkv.x; kv.y += bkv.y; kv.z += bkv.z; kv.w += bkv.w;
      ((float4*)keys_lds)[j*KST4 + sphys] = kv;
    }
  }

  const int grp = tid & 3;
  const int aslot = tid >> 2;

  float4 vreg[16];
  #pragma unroll
  for (int c = 0; c < 16; ++c) vreg[c] = ((const float4*)vvec)[(grp << 4) + c];

  if (tid < HH){
    const float bs = base[(size_t)b*HH + tid];
    base_s[tid] = bs;
    float c0v = 0.f;
    for (int e = 0; e < EE; ++e) c0v = fmaf(tmp1[e], Wq[(size_t)e*HH + tid], c0v);
    q_s[(tid>>6)*68 + (tid&63)] = bs + c0v;
  } else if (tid < HH + NN){
    const int j = tid - HH;
    mask_s[j] = mask_in[(size_t)b*NN + j];
    uint32_t o0,o1; tf2x32(0u, 42u, 0u, (uint32_t)j, o0, o1);
    sk0[j] = o0; sk1[j] = o1;
  } else if (tid == HH + NN){
    out[OFF_INIT + 2*b]     = onode[(size_t)b*NN*2 + 0];
    out[OFF_INIT + 2*b + 1] = onode[(size_t)b*NN*2 + 1];
  } else if (tid >= 512 && tid < 512 + NN){
    on_s[tid - 512] = ((const float2*)onode)[b*NN + (tid - 512)];
  }
  __syncthreads();
  if (tid == 0){
    int L = 0;
    for (int j = 0; j < NN; ++j){
      if (mask_s[j] == 0){ act_s[L] = j; pos_s[j] = L; ++L; }
    }
    L_sh = L;
  }
  if (wid == 15){
    g2_s[0][lane]      = jax_gumbel(sk0[0], sk1[0], (uint32_t)(b*NN + lane));
    g2_s[0][64 + lane] = jax_gumbel(sk0[0], sk1[0], (uint32_t)(b*NN + 64 + lane));
  }

  int cur = 0;

  for (int i = 0; i < NN; ++i){
    __syncthreads();
    const int L = L_sh;
    if (aslot < L){
      const int j = act_s[aslot];
      const int kb4 = j*KST4 + (grp << 4);
      const int qb4 = grp*17;
      float s = 0.f;
      #pragma unroll
      for (int c4 = 0; c4 < 4; ++c4){
        float th[16];
        #pragma unroll
        for (int cc = 0; cc < 4; ++cc){
          const int c = c4*4 + cc;
          const float4 kv = ((const float4*)keys_lds)[kb4 + (c ^ grp)];
          const float4 qv = ((const float4*)q_s)[qb4 + c];
          th[4*cc+0] = fast_tanhf(kv.x + qv.x);
          th[4*cc+1] = fast_tanhf(kv.y + qv.y);
          th[4*cc+2] = fast_tanhf(kv.z + qv.z);
          th[4*cc+3] = fast_tanhf(kv.w + qv.w);
        }
        #pragma unroll
        for (int cc = 0; cc < 4; ++cc){
          const float4 vv = vreg[c4*4 + cc];
          s = fmaf(th[4*cc+0], vv.x, s);
          s = fmaf(th[4*cc+1], vv.y, s);
          s = fmaf(th[4*cc+2], vv.z, s);
          s = fmaf(th[4*cc+3], vv.w, s);
        }
      }
      s += __shfl_xor(s, 1);
      s += __shfl_xor(s, 2);
      if (grp == 0) u_s[j] = s;
    } else if (wid == 15 && i + 1 < NN){
      const int nb = (i + 1) & 1;
      g2_s[nb][lane]      = jax_gumbel(sk0[i+1], sk1[i+1], (uint32_t)(b*NN + lane));
      g2_s[nb][64 + lane] = jax_gumbel(sk0[i+1], sk1[i+1], (uint32_t)(b*NN + 64 + lane));
    }
    __syncthreads();
    float l0 = 0.f, l1 = 0.f; int bi = 0;
    if (wid == 0){
      l0 = 10.0f * fast_tanhf(u_s[lane]);
      l1 = 10.0f * fast_tanhf(u_s[64 + lane]);
      if (mask_s[lane])      l0 = NEG_INF;
      if (mask_s[64 + lane]) l1 = NEG_INF;
      const float y0 = l0 + g2_s[i & 1][lane];
      const float y1 = l1 + g2_s[i & 1][64 + lane];
      float bv;
      if (y1 > y0){ bv = y1; bi = 64 + lane; } else { bv = y0; bi = lane; }
      #pragma unroll
      for (int off = 1; off < 64; off <<= 1){
        const float ov = __shfl_xor(bv, off);
        const int   oi = __shfl_xor(bi, off);
        if (ov > bv || (ov == bv && oi < bi)){ bv = ov; bi = oi; }
      }
      if (i == 0 && id0 == 0) bi = 0;
      if (lane == 0) idx_sh = bi;
    }
    __syncthreads();
    const int idx = idx_sh;
    if (i == 0){
      if (tid < HH){
        const float* arow = lcv + ((size_t)b*NN + idx)*EE;
        float acc = 0.f;
        for (int e = 0; e < EE; ++e) acc = fmaf(arow[e], T1[(size_t)e*HH + tid], acc);
        p1row[tid] = acc;
      }
      __syncthreads();
    }
    if (wid == (idx >> 3)){
      const int r2 = idx & 7;
      float4 pp;
      switch (r2){
        case 0: pp = p2acc[0]; break;
        case 1: pp = p2acc[1]; break;
        case 2: pp = p2acc[2]; break;
        case 3: pp = p2acc[3]; break;
        case 4: pp = p2acc[4]; break;
        case 5: pp = p2acc[5]; break;
        case 6: pp = p2acc[6]; break;
        default: pp = p2acc[7]; break;
      }
      const float4 b4 = ((const float4*)base_s)[lane];
      const float4 p4 = ((const float4*)p1row)[lane];
      float4 nq;
      nq.x = (b4.x + p4.x) + pp.x;
      nq.y = (b4.y + p4.y) + pp.y;
      nq.z = (b4.z + p4.z) + pp.z;
      nq.w = (b4.w + p4.w) + pp.w;
      ((float4*)q_s)[((lane >> 4)*17) + (lane & 15)] = nq;
    }
    if (wid == 0){
      float es = __expf(l0) + __expf(l1);
      #pragma unroll
      for (int off = 1; off < 64; off <<= 1) es += __shfl_xor(es, off);
      const float lown = (bi >= 64) ? l1 : l0;
      const float lsel = __shfl(lown, bi & 63);
      const float logp = lsel - __logf(es);
      if (lane == 0){
        out[OFF_LOGP + b*NN + i] = logp;
        out[OFF_IDX  + b*NN + i] = (float)bi;
        const float2 pc = on_s[cur];
        const float2 pn = on_s[bi];
        const float dx = pn.x - pc.x, dy = pn.y - pc.y;
        out[OFF_RS + b*NN + i] = sqrtf(dx*dx + dy*dy);
        if (i == NN-1){ out[OFF_LAST + 2*b] = pn.x; out[OFF_LAST + 2*b + 1] = pn.y; }
        cur = bi;
        if (mask_s[bi] == 0){
          mask_s[bi] = 1;
          const int p = pos_s[bi];
          const int Lm = L_sh - 1;
          const int last = act_s[Lm];
          act_s[p] = last;
          pos_s[last] = p;
          L_sh = Lm;
        }
      }
    }
  }
}

extern "C" void kernel_launch(void* const* d_in, const int* in_sizes, int n_in,
                              void* d_out, int out_size, void* d_ws, size_t ws_size,
                              hipStream_t stream){
  const float* lcv   = (const float*)d_in[0];
  const float* onode = (const float*)d_in[1];
  const int*   mask  = (const int*)d_in[2];
  const int*   id    = (const int*)d_in[3];
  const float* liw   = (const float*)d_in[4];
  const float* Whbar = (const float*)d_in[5];
  const float* bhbar = (const float*)d_in[6];
  const float* Wrest = (const float*)d_in[7];
  const float* brest = (const float*)d_in[8];
  const float* Wk    = (const float*)d_in[9];
  const float* bk    = (const float*)d_in[10];
  const float* Wq    = (const float*)d_in[11];
  const float* bq    = (const float*)d_in[12];
  const float* vv    = (const float*)d_in[13];

  float* ws  = (float*)d_ws;
  float* out = (float*)d_out;

  const size_t NEED_BASE = 21267200ull * 4ull;   // 81.1 MB
  const size_t NEED_FULL = 25461504ull * 4ull;   // 101.8 MB (adds g_tab)

  if (ws_size >= NEED_BASE){
    float* T1   = ws;                 // 131072
    float* base = ws + 131072;        // 65536
    float* c0   = ws + 196864;        // 256
    float* qb   = ws + 197120;        // 65536
    float* keys = ws + 262912;        // 8388608
    float* P2   = ws + 8651520;       // 8388608
    float* ltab = ws + 17040128;      // 4227072
    float* gtab = (ws_size >= NEED_FULL) ? (ws + 21267200) : (float*)nullptr;

    hipLaunchKernelGGL(k_pre, dim3(gtab ? 1025 : 769), dim3(256), 0, stream,
                       liw, Wrest, Wq, lcv, Whbar, bhbar, brest, bq, c0, T1, base, gtab);
    hipLaunchKernelGGL(k_keysP2, dim3(256), dim3(1024), 0, stream,
                       lcv, Wk, T1, bk, base, c0, vv, mask, id, keys, P2, ltab, qb);
    hipLaunchKernelGGL(k_tab, dim3(1024), dim3(256), 0, stream, keys, P2, qb, vv, ltab);
    hipLaunchKernelGGL(k_seq, dim3(256), dim3(256), 0, stream, ltab, onode, mask, id, gtab, out);
  } else {
    // fallback: round-4 path (known-pass)
    float* T1   = ws;            // 512*256
    float* base = ws + 131072;   // 256*256
    float* tmp1 = ws + 196608;   // 256

    hipLaunchKernelGGL(k_tmp1, dim3(1),   dim3(256), 0, stream, liw, Wrest, tmp1);
    hipLaunchKernelGGL(k_T1,   dim3(512), dim3(256), 0, stream, Wrest, Wq, T1);
    hipLaunchKernelGGL(k_base, dim3(256), dim3(256), 0, stream, lcv, Whbar, bhbar, brest, Wq, bq, base);
    hipLaunchKernelGGL(dec_main, dim3(256), dim3(1024), 0, stream,
                       lcv, onode, mask, id, Wk, bk, vv, T1, base, tmp1, Wq, out);
  }
}

// Round 10
// 445.129 us; speedup vs baseline: 1.0344x; 1.0344x over previous
//
#include <hip/hip_runtime.h>
#include <stdint.h>
#include <math.h>

#define NN 128
#define EE 256
#define HH 256

#define OFF_LOGP 0
#define OFF_IDX  32768
#define OFF_INIT 65536
#define OFF_LAST 66048
#define OFF_RS   66560

// fallback path key stride
#define KST  260
#define KST4 65

__device__ __forceinline__ uint32_t rotl32_(uint32_t x, int d){ return (x<<d)|(x>>(32-d)); }

// Threefry-2x32, 20 rounds, JAX key schedule (bit-identical to rounds 1-9)
__device__ __forceinline__ void tf2x32(uint32_t k0, uint32_t k1, uint32_t x0, uint32_t x1,
                                       uint32_t& o0, uint32_t& o1){
  uint32_t k2 = k0 ^ k1 ^ 0x1BD11BDAu;
  x0 += k0; x1 += k1;
#define TF_RND(r) { x0 += x1; x1 = rotl32_(x1,(r)); x1 ^= x0; }
  TF_RND(13) TF_RND(15) TF_RND(26) TF_RND(6)
  x0 += k1; x1 += k2 + 1u;
  TF_RND(17) TF_RND(29) TF_RND(16) TF_RND(24)
  x0 += k2; x1 += k0 + 2u;
  TF_RND(13) TF_RND(15) TF_RND(26) TF_RND(6)
  x0 += k0; x1 += k1 + 3u;
  TF_RND(17) TF_RND(29) TF_RND(16) TF_RND(24)
  x0 += k1; x1 += k2 + 4u;
  TF_RND(13) TF_RND(15) TF_RND(26) TF_RND(6)
  x0 += k2; x1 += k0 + 5u;
#undef TF_RND
  o0 = x0; o1 = x1;
}

// Refined fast tanh (rounds 4-9, passed): ~0.5 ulp division
__device__ __forceinline__ float fast_tanhf(float x){
  float ax = __builtin_fabsf(x);
  float E = __builtin_amdgcn_exp2f(ax * -2.885390081777927f);
  float num = 1.0f - E;
  float den = 1.0f + E;
  float inv = __builtin_amdgcn_rcpf(den);
  inv = fmaf(fmaf(-den, inv, 1.0f), inv, inv);
  float r = num * inv;
  r = fmaf(fmaf(-den, r, num), inv, r);
  return __builtin_copysignf(r, x);
}

// k_tab inner tanh on PRE-SCALED input xs = x * 2*log2(e) (rounds 7/9, passed)
__device__ __forceinline__ float tanh_pre(float xs){
  float E = __builtin_amdgcn_exp2f(xs);
  return fmaf(-2.0f, __builtin_amdgcn_rcpf(1.0f + E), 1.0f);
}

// jax.random.gumbel element — bit-identical to rounds 1-9
__device__ __forceinline__ float jax_gumbel(uint32_t k0, uint32_t k1, uint32_t t){
  uint32_t o0, o1, bits;
  tf2x32(k0, k1, 0u, t, o0, o1);
  bits = o0 ^ o1;
  float u = __uint_as_float((bits >> 9) | 0x3f800000u) - 1.0f;
  const float kTiny = 1.17549435e-38f;
  u = fmaxf(kTiny, u + kTiny);
  return -logf(-logf(u));
}

// Wave-wide argmax(+sum) reduce (bit-identical to rounds 5-9)
#define CMB_DPP(CTRL) { \
  float ny_ = __int_as_float(__builtin_amdgcn_mov_dpp(__float_as_int(y), (CTRL), 0xf, 0xf, false)); \
  int   nj_ = __builtin_amdgcn_mov_dpp(pj, (CTRL), 0xf, 0xf, false); \
  float ne_ = __int_as_float(__builtin_amdgcn_mov_dpp(__float_as_int(es), (CTRL), 0xf, 0xf, false)); \
  es += ne_; \
  if (ny_ > y || (ny_ == y && nj_ < pj)){ y = ny_; pj = nj_; } }
#define CMB_SWZ16() { \
  float ny_ = __int_as_float(__builtin_amdgcn_ds_swizzle(__float_as_int(y), 0x401F)); \
  int   nj_ = __builtin_amdgcn_ds_swizzle(pj, 0x401F); \
  float ne_ = __int_as_float(__builtin_amdgcn_ds_swizzle(__float_as_int(es), 0x401F)); \
  es += ne_; \
  if (ny_ > y || (ny_ == y && nj_ < pj)){ y = ny_; pj = nj_; } }
#define CMB_SHF32() { \
  float ny_ = __shfl_xor(y, 32); \
  int   nj_ = __shfl_xor(pj, 32); \
  float ne_ = __shfl_xor(es, 32); \
  es += ne_; \
  if (ny_ > y || (ny_ == y && nj_ < pj)){ y = ny_; pj = nj_; } }

// ============ K1: fused precompute + optional gumbel table ============
// blocks: 0 = tmp1+c0 | 1..512 = T1 | 513..768 = base | 769..1024 = gumbel (if g_tab)
__global__ __launch_bounds__(256) void k_pre(
    const float* __restrict__ liw, const float* __restrict__ Wr,
    const float* __restrict__ Wq, const float* __restrict__ lcv,
    const float* __restrict__ Whbar, const float* __restrict__ bhbar,
    const float* __restrict__ brest, const float* __restrict__ bq,
    float* __restrict__ c0, float* __restrict__ T1, float* __restrict__ base,
    float* __restrict__ g_tab)
{
  __shared__ float sbuf[512];
  __shared__ uint32_t gk0[NN], gk1[NN];
  const int bid = blockIdx.x;
  const int t = threadIdx.x;
  if (bid == 0){
    float acc = 0.f;
    for (int k = 0; k < 2*EE; ++k) acc = fmaf(liw[k], Wr[(size_t)k*EE + t], acc);
    sbuf[t] = acc;
    __syncthreads();
    float c = 0.f;
    for (int e = 0; e < EE; ++e) c = fmaf(sbuf[e], Wq[(size_t)e*HH + t], c);
    c0[t] = c;
  } else if (bid <= 512){
    const int r = bid - 1;
    float acc = 0.f;
    for (int e = 0; e < EE; ++e) acc = fmaf(Wr[(size_t)r*EE + e], Wq[(size_t)e*HH + t], acc);
    T1[(size_t)r*HH + t] = acc;
  } else if (bid <= 768){
    const int b = bid - 513;
    float* sm  = sbuf;
    float* hb2 = sbuf + 256;
    float acc = 0.f;
    const float* p = lcv + (size_t)b*NN*EE + t;
    for (int n = 0; n < NN; ++n) acc += p[(size_t)n*EE];
    sm[t] = acc * 0.0078125f;
    __syncthreads();
    float a2 = 0.f;
    for (int e = 0; e < EE; ++e) a2 = fmaf(sm[e], Whbar[(size_t)e*EE + t], a2);
    hb2[t] = (a2 + bhbar[t]) + brest[t];
    __syncthreads();
    float a3 = 0.f;
    for (int e = 0; e < EE; ++e) a3 = fmaf(hb2[e], Wq[(size_t)e*HH + t], a3);
    base[(size_t)b*HH + t] = a3 + bq[t];
  } else {
    // gumbel table for batch b2 (bit-identical values to k_seq's internal gen)
    const int b2 = bid - 769;
    if (t < NN){
      uint32_t o0, o1; tf2x32(0u, 42u, 0u, (uint32_t)t, o0, o1);
      gk0[t] = o0; gk1[t] = o1;
    }
    __syncthreads();
    for (int k = 0; k < 64; ++k){
      const int p = t + 256*k;
      const int i = p >> 7, j = p & 127;
      g_tab[(size_t)b2*16384 + p] = jax_gumbel(gk0[i], gk1[i], (uint32_t)(b2*NN + j));
    }
  }
}

// ============ K2: keys/P2 GEMM + fused l0 row + fused idx0 + qb ============
__global__ __launch_bounds__(1024) void k_keysP2(
    const float* __restrict__ lcv, const float* __restrict__ Wk,
    const float* __restrict__ T1, const float* __restrict__ bk,
    const float* __restrict__ base, const float* __restrict__ c0,
    const float* __restrict__ vvec, const int* __restrict__ mask_in,
    const int* __restrict__ id_in,
    float* __restrict__ keysg, float* __restrict__ P2g, float* __restrict__ ltab,
    float* __restrict__ qbg)
{
  const int b = blockIdx.x, tid = threadIdx.x, wid = tid >> 6, lane = tid & 63;
  __shared__ __align__(16) float sbuf[20992];   // sA[128][36] + sW[32][256] + sT[32][256]
  __shared__ __align__(16) float q0s[EE];
  __shared__ __align__(16) float vs[EE];
  __shared__ float l0s[NN];
  __shared__ int idx_sh;
  float* sA = sbuf;
  float* sW = sbuf + 4608;
  float* sT = sbuf + 12800;
  if (tid < 64){
    float4 bs = ((const float4*)(base + (size_t)b*HH))[tid];
    const float4 cc = ((const float4*)c0)[tid];
    bs.x += cc.x; bs.y += cc.y; bs.z += cc.z; bs.w += cc.w;
    ((float4*)q0s)[tid] = bs;
    ((float4*)vs)[tid]  = ((const float4*)vvec)[tid];
  }
  float4 kacc[8], p2acc[8];
  #pragma unroll
  for (int r = 0; r < 8; ++r){
    kacc[r]  = make_float4(0.f,0.f,0.f,0.f);
    p2acc[r] = make_float4(0.f,0.f,0.f,0.f);
  }
  for (int ch = 0; ch < 8; ++ch){
    const int e0 = ch << 5;
    __syncthreads();
    {
      const int r = tid >> 3, c = tid & 7;
      const float4 t = ((const float4*)(lcv + ((size_t)b*NN + r)*EE + e0))[c];
      ((float4*)sA)[r*9 + c] = t;
    }
    #pragma unroll
    for (int s = 0; s < 2; ++s){
      const int idx4 = s*1024 + tid;
      const int e = idx4 >> 6, c = idx4 & 63;
      ((float4*)sW)[idx4] = ((const float4*)(Wk + (size_t)(e0+e)*HH))[c];
      ((float4*)sT)[idx4] = ((const float4*)(T1 + (size_t)(EE+e0+e)*HH))[c];
    }
    __syncthreads();
    const float* aRow = sA + (wid << 3)*36;
    for (int e = 0; e < 32; ++e){
      const float4 wv = ((const float4*)sW)[(e<<6) + lane];
      const float4 tv = ((const float4*)sT)[(e<<6) + lane];
      #pragma unroll
      for (int r = 0; r < 8; ++r){
        const float av = aRow[r*36 + e];
        kacc[r].x = fmaf(av, wv.x, kacc[r].x);
        kacc[r].y = fmaf(av, wv.y, kacc[r].y);
        kacc[r].z = fmaf(av, wv.z, kacc[r].z);
        kacc[r].w = fmaf(av, wv.w, kacc[r].w);
        p2acc[r].x = fmaf(av, tv.x, p2acc[r].x);
        p2acc[r].y = fmaf(av, tv.y, p2acc[r].y);
        p2acc[r].z = fmaf(av, tv.z, p2acc[r].z);
        p2acc[r].w = fmaf(av, tv.w, p2acc[r].w);
      }
    }
  }
  const float4 bkv = ((const float4*)bk)[lane];
  const float4 qv0 = ((const float4*)q0s)[lane];
  const float4 vv0 = ((const float4*)vs)[lane];
  #pragma unroll
  for (int r = 0; r < 8; ++r){
    const int j = (wid << 3) + r;
    float4 kv = kacc[r];
    kv.x += bkv.x; kv.y += bkv.y; kv.z += bkv.z; kv.w += bkv.w;
    ((float4*)(keysg + ((size_t)b*NN + j)*EE))[lane] = kv;
    ((float4*)(P2g   + ((size_t)b*NN + j)*EE))[lane] = p2acc[r];
    float p = 0.f;
    p = fmaf(fast_tanhf(kv.x + qv0.x), vv0.x, p);
    p = fmaf(fast_tanhf(kv.y + qv0.y), vv0.y, p);
    p = fmaf(fast_tanhf(kv.z + qv0.z), vv0.z, p);
    p = fmaf(fast_tanhf(kv.w + qv0.w), vv0.w, p);
    #pragma unroll
    for (int off = 1; off < 64; off <<= 1) p += __shfl_xor(p, off);
    if (lane == 0){
      const float lv = 10.0f * fast_tanhf(p);
      ltab[((size_t)b*129 + 128)*NN + j] = lv;
      l0s[j] = lv;
    }
  }
  __syncthreads();
  // fused idx0 (identical algorithm/values to round-6/7 k_idx0qb)
  if (tid < 64){
    const float NEG_INF = -__builtin_huge_valf();
    float l0 = l0s[lane];
    float l1 = l0s[64 + lane];
    if (mask_in[(size_t)b*NN + lane])      l0 = NEG_INF;
    if (mask_in[(size_t)b*NN + 64 + lane]) l1 = NEG_INF;
    uint32_t k0, k1; tf2x32(0u, 42u, 0u, 0u, k0, k1);
    const float g0 = jax_gumbel(k0, k1, (uint32_t)(b*NN + lane));
    const float g1 = jax_gumbel(k0, k1, (uint32_t)(b*NN + 64 + lane));
    float y = l0 + g0; int pj = lane;
    { float yb = l1 + g1; if (yb > y){ y = yb; pj = 64 + lane; } }
    float es = 0.f;   // unused
    CMB_DPP(0xB1); CMB_DPP(0x4E); CMB_DPP(0x124); CMB_DPP(0x128);
    CMB_SWZ16(); CMB_SHF32();
    int bi = pj;
    if (id_in[0] == 0) bi = 0;
    if (lane == 0) idx_sh = bi;
  }
  __syncthreads();
  // fused qb GEMV (identical sequential e-order)
  if (tid < HH){
    const float* arow = lcv + ((size_t)b*NN + idx_sh)*EE;
    float acc = 0.f;
    #pragma unroll 4
    for (int e = 0; e < EE; ++e) acc = fmaf(arow[e], T1[(size_t)e*HH + tid], acc);
    qbg[(size_t)b*HH + tid] = base[(size_t)b*HH + tid] + acc;
  }
}

// ============ K3: the big table — ROUND-7 VERSION (conflict-free layout) ============
// l_tab[b][idx][j] = 10*tanh(sum_h tanh_pre(ckeys[j,h] + cQ2[idx,h]) * v[h])
// 4 rows/thread (jq = t&7): a wave reads 8 distinct key rows per ds_read ->
// (4(jq&1)+(hc^jq)) mod 8 is a permutation -> conflict-free (r9's 16-row
// variant was inherently 2-way-conflicted: 17.7M conflicts, -8% perf).
__global__ __launch_bounds__(256) void k_tab(
    const float* __restrict__ keysg, const float* __restrict__ P2g,
    const float* __restrict__ qb, const float* __restrict__ vvec,
    float* __restrict__ l_tab)
{
  const int b  = blockIdx.x >> 2;
  const int jt = blockIdx.x & 3;
  const int t = threadIdx.x;
  const float CSC = 2.885390081777927f;            // 2*log2(e)
  __shared__ __align__(16) float skeys[32*65*4];   // [32 rows][65 f4], xor-swizzled, *CSC
  __shared__ __align__(16) float sQ2[32*65*4];     // [32 rows][65 f4], (P2+qb)*CSC
  __shared__ __align__(16) float sv[EE];
  __shared__ __align__(16) float sqbc[EE];         // qb*CSC

  #pragma unroll
  for (int k = 0; k < 8; ++k){
    const int idx4 = t + 256*k;                // 0..2047
    const int row = idx4 >> 6, hc = idx4 & 63;
    float4 kv = ((const float4*)(keysg + ((size_t)b*NN + jt*32 + row)*EE))[hc];
    kv.x *= CSC; kv.y *= CSC; kv.z *= CSC; kv.w *= CSC;
    ((float4*)skeys)[row*65 + (hc ^ ((row >> 2) & 7))] = kv;
  }
  if (t < 64){
    ((float4*)sv)[t]  = ((const float4*)vvec)[t];
    float4 qv = ((const float4*)(qb + (size_t)b*HH))[t];
    qv.x *= CSC; qv.y *= CSC; qv.z *= CSC; qv.w *= CSC;
    ((float4*)sqbc)[t] = qv;
  }
  const int jq = t & 7;       // j-quad: j = jq*4 + jj
  const int iq = t >> 3;      // idx within 32-chunk

  // prefetch P2 chunk for ib=0 into registers
  float4 pr[8];
  #pragma unroll
  for (int k = 0; k < 8; ++k){
    const int idx4 = t + 256*k;
    const int row = idx4 >> 6, hc = idx4 & 63;
    pr[k] = ((const float4*)(P2g + ((size_t)b*NN + row)*EE))[hc];
  }

  for (int ib = 0; ib < 4; ++ib){
    __syncthreads();
    #pragma unroll
    for (int k = 0; k < 8; ++k){
      const int idx4 = t + 256*k;
      const int row = idx4 >> 6, hc = idx4 & 63;
      const float4 qv = ((const float4*)sqbc)[hc];
      float4 pv;
      pv.x = fmaf(pr[k].x, CSC, qv.x);
      pv.y = fmaf(pr[k].y, CSC, qv.y);
      pv.z = fmaf(pr[k].z, CSC, qv.z);
      pv.w = fmaf(pr[k].w, CSC, qv.w);
      ((float4*)sQ2)[row*65 + hc] = pv;
    }
    if (ib + 1 < 4){   // issue next chunk's loads; complete under compute
      #pragma unroll
      for (int k = 0; k < 8; ++k){
        const int idx4 = t + 256*k;
        const int row = idx4 >> 6, hc = idx4 & 63;
        pr[k] = ((const float4*)(P2g + ((size_t)b*NN + (ib+1)*32 + row)*EE))[hc];
      }
    }
    __syncthreads();
    float a0 = 0.f, a1 = 0.f, a2 = 0.f, a3 = 0.f;
    #pragma unroll 2
    for (int hc = 0; hc < 64; ++hc){
      const float4 qv = ((const float4*)sQ2)[iq*65 + hc];
      const float4 vv = ((const float4*)sv)[hc];
      const int hx = hc ^ jq;                  // matches write swizzle ((row>>2)&7)=jq
      const float4 k0 = ((const float4*)skeys)[(jq*4 + 0)*65 + hx];
      const float4 k1 = ((const float4*)skeys)[(jq*4 + 1)*65 + hx];
      const float4 k2 = ((const float4*)skeys)[(jq*4 + 2)*65 + hx];
      const float4 k3 = ((const float4*)skeys)[(jq*4 + 3)*65 + hx];
      a0 = fmaf(tanh_pre(k0.x + qv.x), vv.x, a0);
      a0 = fmaf(tanh_pre(k0.y + qv.y), vv.y, a0);
      a0 = fmaf(tanh_pre(k0.z + qv.z), vv.z, a0);
      a0 = fmaf(tanh_pre(k0.w + qv.w), vv.w, a0);
      a1 = fmaf(tanh_pre(k1.x + qv.x), vv.x, a1);
      a1 = fmaf(tanh_pre(k1.y + qv.y), vv.y, a1);
      a1 = fmaf(tanh_pre(k1.z + qv.z), vv.z, a1);
      a1 = fmaf(tanh_pre(k1.w + qv.w), vv.w, a1);
      a2 = fmaf(tanh_pre(k2.x + qv.x), vv.x, a2);
      a2 = fmaf(tanh_pre(k2.y + qv.y), vv.y, a2);
      a2 = fmaf(tanh_pre(k2.z + qv.z), vv.z, a2);
      a2 = fmaf(tanh_pre(k2.w + qv.w), vv.w, a2);
      a3 = fmaf(tanh_pre(k3.x + qv.x), vv.x, a3);
      a3 = fmaf(tanh_pre(k3.y + qv.y), vv.y, a3);
      a3 = fmaf(tanh_pre(k3.z + qv.z), vv.z, a3);
      a3 = fmaf(tanh_pre(k3.w + qv.w), vv.w, a3);
    }
    const int idx = ib*32 + iq;
    float* dst = l_tab + ((size_t)b*129 + idx)*NN + jt*32 + jq*4;
    dst[0] = 10.0f * fast_tanhf(a0);
    dst[1] = 10.0f * fast_tanhf(a1);
    dst[2] = 10.0f * fast_tanhf(a2);
    dst[3] = 10.0f * fast_tanhf(a3);
  }
}

// ============ K4: sequential sampler (g_tab-aware) ============
__global__ __launch_bounds__(256) void k_seq(
    const float* __restrict__ l_tab, const float* __restrict__ onode,
    const int* __restrict__ mask_in, const int* __restrict__ id_in,
    const float* __restrict__ g_tab, float* __restrict__ out)
{
  const int b = blockIdx.x;
  const int tid = threadIdx.x;
  const int wid = tid >> 6;
  const int lane = tid & 63;
  __shared__ float l_s[129*NN];      // 66048 B
  __shared__ float g_a[NN*NN];       // 65536 B
  __shared__ float2 on_s[NN];
  __shared__ int   mask_s[NN];
  __shared__ uint32_t sk0[NN], sk1[NN];

  #pragma unroll
  for (int k = 0; k < 17; ++k){
    const int i4 = tid + 256*k;
    if (i4 < (129*NN)/4)
      ((float4*)l_s)[i4] = ((const float4*)(l_tab + (size_t)b*129*NN))[i4];
  }
  if (tid < NN){
    mask_s[tid] = mask_in[(size_t)b*NN + tid];
    on_s[tid] = ((const float2*)onode)[b*NN + tid];
    if (!g_tab){
      uint32_t o0, o1; tf2x32(0u, 42u, 0u, (uint32_t)tid, o0, o1);
      sk0[tid] = o0; sk1[tid] = o1;
    }
  }
  if (g_tab){
    #pragma unroll
    for (int k = 0; k < 16; ++k)
      ((float4*)g_a)[tid + 256*k] = ((const float4*)(g_tab + (size_t)b*16384))[tid + 256*k];
    __syncthreads();
  } else {
    __syncthreads();
    for (int k = 0; k < 64; ++k){
      const int p = tid + 256*k;
      const int i = p >> 7, j = p & 127;
      g_a[p] = jax_gumbel(sk0[i], sk1[i], (uint32_t)(b*NN + j));
    }
    __syncthreads();
  }
  if (wid != 0) return;

  const int id0 = id_in[0];
  const float NEG_INF = -__builtin_huge_valf();
  if (lane == 0){
    out[OFF_INIT + 2*b]     = on_s[0].x;
    out[OFF_INIT + 2*b + 1] = on_s[0].y;
  }
  int prev = 128, cur = 0;
  for (int i = 0; i < NN; ++i){
    float l0 = l_s[prev*NN + lane];
    float l1 = l_s[prev*NN + 64 + lane];
    if (mask_s[lane])      l0 = NEG_INF;
    if (mask_s[64 + lane]) l1 = NEG_INF;
    float y = l0 + g_a[i*NN + lane]; int pj = lane;
    { float yb = l1 + g_a[i*NN + 64 + lane];
      if (yb > y){ y = yb; pj = 64 + lane; } }
    float es = __expf(l0) + __expf(l1);
    CMB_DPP(0xB1); CMB_DPP(0x4E); CMB_DPP(0x124); CMB_DPP(0x128);
    CMB_SWZ16(); CMB_SHF32();
    int bi = pj;
    if (i == 0 && id0 == 0) bi = 0;
    const float lsel = __shfl((bi & 64) ? l1 : l0, bi & 63);
    const float logp = lsel - __logf(es);
    if (lane == 0){
      out[OFF_LOGP + b*NN + i] = logp;
      out[OFF_IDX  + b*NN + i] = (float)bi;
      const float2 pc = on_s[cur];
      const float2 pn = on_s[bi];
      const float dx = pn.x - pc.x, dy = pn.y - pc.y;
      out[OFF_RS + b*NN + i] = sqrtf(dx*dx + dy*dy);
      if (i == NN-1){ out[OFF_LAST + 2*b] = pn.x; out[OFF_LAST + 2*b + 1] = pn.y; }
      mask_s[bi] = 1;
      cur = bi;
    }
    prev = bi;
  }
}

// ================= FALLBACK path kernels (round-4, known-pass) =================
__global__ void k_tmp1(const float* __restrict__ liw, const float* __restrict__ Wr,
                       float* __restrict__ tmp1){
  int e = threadIdx.x;
  float acc = 0.f;
  for (int k = 0; k < 2*EE; ++k) acc = fmaf(liw[k], Wr[(size_t)k*EE + e], acc);
  tmp1[e] = acc;
}

__global__ void k_T1(const float* __restrict__ Wr, const float* __restrict__ Wq,
                     float* __restrict__ T1){
  int r = blockIdx.x, h = threadIdx.x;
  float acc = 0.f;
  for (int e = 0; e < EE; ++e) acc = fmaf(Wr[(size_t)r*EE + e], Wq[(size_t)e*HH + h], acc);
  T1[(size_t)r*HH + h] = acc;
}

__global__ void k_base(const float* __restrict__ lcv, const float* __restrict__ Whbar,
                       const float* __restrict__ bhbar, const float* __restrict__ brest,
                       const float* __restrict__ Wq, const float* __restrict__ bq,
                       float* __restrict__ base){
  __shared__ float sm[EE];
  __shared__ float hb2[EE];
  int b = blockIdx.x, t = threadIdx.x;
  float acc = 0.f;
  const float* p = lcv + (size_t)b*NN*EE + t;
  for (int n = 0; n < NN; ++n) acc += p[(size_t)n*EE];
  sm[t] = acc * 0.0078125f;
  __syncthreads();
  float a2 = 0.f;
  for (int e = 0; e < EE; ++e) a2 = fmaf(sm[e], Whbar[(size_t)e*EE + t], a2);
  hb2[t] = (a2 + bhbar[t]) + brest[t];
  __syncthreads();
  float a3 = 0.f;
  for (int e = 0; e < EE; ++e) a3 = fmaf(hb2[e], Wq[(size_t)e*HH + t], a3);
  base[(size_t)b*HH + t] = a3 + bq[t];
}

__global__ __launch_bounds__(1024, 4) void dec_main(
    const float* __restrict__ lcv, const float* __restrict__ onode,
    const int* __restrict__ mask_in, const int* __restrict__ id_in,
    const float* __restrict__ Wk, const float* __restrict__ bk,
    const float* __restrict__ vvec, const float* __restrict__ T1,
    const float* __restrict__ base, const float* __restrict__ tmp1,
    const float* __restrict__ Wq, float* __restrict__ out)
{
  const int b = blockIdx.x;
  const int tid = threadIdx.x;
  const int wid = tid >> 6;
  const int lane = tid & 63;

  __shared__ __align__(16) float keys_lds[NN*KST];
  __shared__ __align__(16) float q_s[272];
  __shared__ __align__(16) float base_s[HH];
  __shared__ __align__(16) float p1row[HH];
  __shared__ __align__(16) float2 on_s[NN];
  __shared__ float u_s[NN];
  __shared__ float g2_s[2][NN];
  __shared__ int act_s[NN];
  __shared__ int pos_s[NN];
  __shared__ int mask_s[NN];
  __shared__ uint32_t sk0[NN], sk1[NN];
  __shared__ int idx_sh, L_sh;

  const float NEG_INF = -__builtin_huge_valf();
  const int id0 = id_in[0];

  float4 kacc[8], p2acc[8];
  #pragma unroll
  for (int r = 0; r < 8; ++r){
    kacc[r]  = make_float4(0.f,0.f,0.f,0.f);
    p2acc[r] = make_float4(0.f,0.f,0.f,0.f);
  }
  {
    float* sA = keys_lds;
    float* sW = keys_lds + 4608;
    float* sT = keys_lds + 12800;
    for (int ch = 0; ch < 8; ++ch){
      const int e0 = ch << 5;
      __syncthreads();
      {
        const int r = tid >> 3, c = tid & 7;
        const float4 t = ((const float4*)(lcv + ((size_t)b*NN + r)*EE + e0))[c];
        ((float4*)sA)[r*9 + c] = t;
      }
      #pragma unroll
      for (int s = 0; s < 2; ++s){
        const int idx4 = s*1024 + tid;
        const int e = idx4 >> 6, c = idx4 & 63;
        ((float4*)sW)[idx4] = ((const float4*)(Wk + (size_t)(e0+e)*HH))[c];
        ((float4*)sT)[idx4] = ((const float4*)(T1 + (size_t)(EE+e0+e)*HH))[c];
      }
      __syncthreads();
      const float* aRow = sA + (wid << 3)*36;
      for (int e = 0; e < 32; ++e){
        const float4 wv = ((const float4*)sW)[(e<<6) + lane];
        const float4 tv = ((const float4*)sT)[(e<<6) + lane];
        #pragma unroll
        for (int r = 0; r < 8; ++r){
          const float av = aRow[r*36 + e];
          kacc[r].x = fmaf(av, wv.x, kacc[r].x);
          kacc[r].y = fmaf(av, wv.y, kacc[r].y);
          kacc[r].z = fmaf(av, wv.z, kacc[r].z);
          kacc[r].w = fmaf(av, wv.w, kacc[r].w);
          p2acc[r].x = fmaf(av, tv.x, p2acc[r].x);
          p2acc[r].y = fmaf(av, tv.y, p2acc[r].y);
          p2acc[r].z = fmaf(av, tv.z, p2acc[r].z);
          p2acc[r].w = fmaf(av, tv.w, p2acc[r].w);
        }
      }
    }
  }
  __syncthreads();
  {
    const float4 bkv = ((const float4*)bk)[lane];
    const int sphys = ((lane >> 4) << 4) | ((lane & 15) ^ (lane >> 4));
    #pragma unroll
    for (int r = 0; r < 8; ++r){
      const int j = (wid << 3) + r;
      float4 kv = kacc[r];
      kv.x += bkv.x; kv.y += bkv.y; kv.z += bkv.z; kv.w += bkv.w;
      ((float4*)keys_lds)[j*KST4 + sphys] = kv;
    }
  }

  const int grp = tid & 3;
  const int aslot = tid >> 2;

  float4 vreg[16];
  #pragma unroll
  for (int c = 0; c < 16; ++c) vreg[c] = ((const float4*)vvec)[(grp << 4) + c];

  if (tid < HH){
    const float bs = base[(size_t)b*HH + tid];
    base_s[tid] = bs;
    float c0v = 0.f;
    for (int e = 0; e < EE; ++e) c0v = fmaf(tmp1[e], Wq[(size_t)e*HH + tid], c0v);
    q_s[(tid>>6)*68 + (tid&63)] = bs + c0v;
  } else if (tid < HH + NN){
    const int j = tid - HH;
    mask_s[j] = mask_in[(size_t)b*NN + j];
    uint32_t o0,o1; tf2x32(0u, 42u, 0u, (uint32_t)j, o0, o1);
    sk0[j] = o0; sk1[j] = o1;
  } else if (tid == HH + NN){
    out[OFF_INIT + 2*b]     = onode[(size_t)b*NN*2 + 0];
    out[OFF_INIT + 2*b + 1] = onode[(size_t)b*NN*2 + 1];
  } else if (tid >= 512 && tid < 512 + NN){
    on_s[tid - 512] = ((const float2*)onode)[b*NN + (tid - 512)];
  }
  __syncthreads();
  if (tid == 0){
    int L = 0;
    for (int j = 0; j < NN; ++j){
      if (mask_s[j] == 0){ act_s[L] = j; pos_s[j] = L; ++L; }
    }
    L_sh = L;
  }
  if (wid == 15){
    g2_s[0][lane]      = jax_gumbel(sk0[0], sk1[0], (uint32_t)(b*NN + lane));
    g2_s[0][64 + lane] = jax_gumbel(sk0[0], sk1[0], (uint32_t)(b*NN + 64 + lane));
  }

  int cur = 0;

  for (int i = 0; i < NN; ++i){
    __syncthreads();
    const int L = L_sh;
    if (aslot < L){
      const int j = act_s[aslot];
      const int kb4 = j*KST4 + (grp << 4);
      const int qb4 = grp*17;
      float s = 0.f;
      #pragma unroll
      for (int c4 = 0; c4 < 4; ++c4){
        float th[16];
        #pragma unroll
        for (int cc = 0; cc < 4; ++cc){
          const int c = c4*4 + cc;
          const float4 kv = ((const float4*)keys_lds)[kb4 + (c ^ grp)];
          const float4 qv = ((const float4*)q_s)[qb4 + c];
          th[4*cc+0] = fast_tanhf(kv.x + qv.x);
          th[4*cc+1] = fast_tanhf(kv.y + qv.y);
          th[4*cc+2] = fast_tanhf(kv.z + qv.z);
          th[4*cc+3] = fast_tanhf(kv.w + qv.w);
        }
        #pragma unroll
        for (int cc = 0; cc < 4; ++cc){
          const float4 vv = vreg[c4*4 + cc];
          s = fmaf(th[4*cc+0], vv.x, s);
          s = fmaf(th[4*cc+1], vv.y, s);
          s = fmaf(th[4*cc+2], vv.z, s);
          s = fmaf(th[4*cc+3], vv.w, s);
        }
      }
      s += __shfl_xor(s, 1);
      s += __shfl_xor(s, 2);
      if (grp == 0) u_s[j] = s;
    } else if (wid == 15 && i + 1 < NN){
      const int nb = (i + 1) & 1;
      g2_s[nb][lane]      = jax_gumbel(sk0[i+1], sk1[i+1], (uint32_t)(b*NN + lane));
      g2_s[nb][64 + lane] = jax_gumbel(sk0[i+1], sk1[i+1], (uint32_t)(b*NN + 64 + lane));
    }
    __syncthreads();
    float l0 = 0.f, l1 = 0.f; int bi = 0;
    if (wid == 0){
      l0 = 10.0f * fast_tanhf(u_s[lane]);
      l1 = 10.0f * fast_tanhf(u_s[64 + lane]);
      if (mask_s[lane])      l0 = NEG_INF;
      if (mask_s[64 + lane]) l1 = NEG_INF;
      const float y0 = l0 + g2_s[i & 1][lane];
      const float y1 = l1 + g2_s[i & 1][64 + lane];
      float bv;
      if (y1 > y0){ bv = y1; bi = 64 + lane; } else { bv = y0; bi = lane; }
      #pragma unroll
      for (int off = 1; off < 64; off <<= 1){
        const float ov = __shfl_xor(bv, off);
        const int   oi = __shfl_xor(bi, off);
        if (ov > bv || (ov == bv && oi < bi)){ bv = ov; bi = oi; }
      }
      if (i == 0 && id0 == 0) bi = 0;
      if (lane == 0) idx_sh = bi;
    }
    __syncthreads();
    const int idx = idx_sh;
    if (i == 0){
      if (tid < HH){
        const float* arow = lcv + ((size_t)b*NN + idx)*EE;
        float acc = 0.f;
        for (int e = 0; e < EE; ++e) acc = fmaf(arow[e], T1[(size_t)e*HH + tid], acc);
        p1row[tid] = acc;
      }
      __syncthreads();
    }
    if (wid == (idx >> 3)){
      const int r2 = idx & 7;
      float4 pp;
      switch (r2){
        case 0: pp = p2acc[0]; break;
        case 1: pp = p2acc[1]; break;
        case 2: pp = p2acc[2]; break;
        case 3: pp = p2acc[3]; break;
        case 4: pp = p2acc[4]; break;
        case 5: pp = p2acc[5]; break;
        case 6: pp = p2acc[6]; break;
        default: pp = p2acc[7]; break;
      }
      const float4 b4 = ((const float4*)base_s)[lane];
      const float4 p4 = ((const float4*)p1row)[lane];
      float4 nq;
      nq.x = (b4.x + p4.x) + pp.x;
      nq.y = (b4.y + p4.y) + pp.y;
      nq.z = (b4.z + p4.z) + pp.z;
      nq.w = (b4.w + p4.w) + pp.w;
      ((float4*)q_s)[((lane >> 4)*17) + (lane & 15)] = nq;
    }
    if (wid == 0){
      float es = __expf(l0) + __expf(l1);
      #pragma unroll
      for (int off = 1; off < 64; off <<= 1) es += __shfl_xor(es, off);
      const float lown = (bi >= 64) ? l1 : l0;
      const float lsel = __shfl(lown, bi & 63);
      const float logp = lsel - __logf(es);
      if (lane == 0){
        out[OFF_LOGP + b*NN + i] = logp;
        out[OFF_IDX  + b*NN + i] = (float)bi;
        const float2 pc = on_s[cur];
        const float2 pn = on_s[bi];
        const float dx = pn.x - pc.x, dy = pn.y - pc.y;
        out[OFF_RS + b*NN + i] = sqrtf(dx*dx + dy*dy);
        if (i == NN-1){ out[OFF_LAST + 2*b] = pn.x; out[OFF_LAST + 2*b + 1] = pn.y; }
        cur = bi;
        if (mask_s[bi] == 0){
          mask_s[bi] = 1;
          const int p = pos_s[bi];
          const int Lm = L_sh - 1;
          const int last = act_s[Lm];
          act_s[p] = last;
          pos_s[last] = p;
          L_sh = Lm;
        }
      }
    }
  }
}

extern "C" void kernel_launch(void* const* d_in, const int* in_sizes, int n_in,
                              void* d_out, int out_size, void* d_ws, size_t ws_size,
                              hipStream_t stream){
  const float* lcv   = (const float*)d_in[0];
  const float* onode = (const float*)d_in[1];
  const int*   mask  = (const int*)d_in[2];
  const int*   id    = (const int*)d_in[3];
  const float* liw   = (const float*)d_in[4];
  const float* Whbar = (const float*)d_in[5];
  const float* bhbar = (const float*)d_in[6];
  const float* Wrest = (const float*)d_in[7];
  const float* brest = (const float*)d_in[8];
  const float* Wk    = (const float*)d_in[9];
  const float* bk    = (const float*)d_in[10];
  const float* Wq    = (const float*)d_in[11];
  const float* bq    = (const float*)d_in[12];
  const float* vv    = (const float*)d_in[13];

  float* ws  = (float*)d_ws;
  float* out = (float*)d_out;

  const size_t NEED_BASE = 21267200ull * 4ull;   // 81.1 MB
  const size_t NEED_FULL = 25461504ull * 4ull;   // 101.8 MB (adds g_tab)

  if (ws_size >= NEED_BASE){
    float* T1   = ws;                 // 131072
    float* base = ws + 131072;        // 65536
    float* c0   = ws + 196864;        // 256
    float* qb   = ws + 197120;        // 65536
    float* keys = ws + 262912;        // 8388608
    float* P2   = ws + 8651520;       // 8388608
    float* ltab = ws + 17040128;      // 4227072
    float* gtab = (ws_size >= NEED_FULL) ? (ws + 21267200) : (float*)nullptr;

    hipLaunchKernelGGL(k_pre, dim3(gtab ? 1025 : 769), dim3(256), 0, stream,
                       liw, Wrest, Wq, lcv, Whbar, bhbar, brest, bq, c0, T1, base, gtab);
    hipLaunchKernelGGL(k_keysP2, dim3(256), dim3(1024), 0, stream,
                       lcv, Wk, T1, bk, base, c0, vv, mask, id, keys, P2, ltab, qb);
    hipLaunchKernelGGL(k_tab, dim3(1024), dim3(256), 0, stream, keys, P2, qb, vv, ltab);
    hipLaunchKernelGGL(k_seq, dim3(256), dim3(256), 0, stream, ltab, onode, mask, id, gtab, out);
  } else {
    // fallback: round-4 path (known-pass)
    float* T1   = ws;            // 512*256
    float* base = ws + 131072;   // 256*256
    float* tmp1 = ws + 196608;   // 256

    hipLaunchKernelGGL(k_tmp1, dim3(1),   dim3(256), 0, stream, liw, Wrest, tmp1);
    hipLaunchKernelGGL(k_T1,   dim3(512), dim3(256), 0, stream, Wrest, Wq, T1);
    hipLaunchKernelGGL(k_base, dim3(256), dim3(256), 0, stream, lcv, Whbar, bhbar, brest, Wq, bq, base);
    hipLaunchKernelGGL(dec_main, dim3(256), dim3(1024), 0, stream,
                       lcv, onode, mask, id, Wk, bk, vv, T1, base, tmp1, Wq, out);
  }
}